// Round 1
// baseline (2209.747 us; speedup 1.0000x reference)
//
#include <hip/hip_runtime.h>
#include <cstddef>
#include <cstdint>

#define D_MODEL 1024
#define D_STATE 16
#define D_CONV 4
#define D_INNER 2048
#define IN_DIM 256
#define OUT_DIM 256
#define BATCH 2
#define SEQ 1024
#define NTOK (BATCH*SEQ)
#define XZ_N (2*D_INNER)            // 4096
#define PROJ_N (2*D_STATE + D_INNER) // 2080

__device__ __forceinline__ float siluf(float x){ return x / (1.f + __expf(-x)); }

// C[M,N] = act(A[M,K] (row stride lda) * B[K,N] + bias); act: 0=none, 1=softplus
__global__ __launch_bounds__(256)
void gemm_f32(const float* __restrict__ A, const float* __restrict__ B,
              const float* __restrict__ bias, float* __restrict__ C,
              int M, int N, int K, int lda, int act)
{
  __shared__ float As[16][64];   // [k][m]
  __shared__ float Bs[16][64];   // [k][n]
  const int tid = threadIdx.x;
  const int tx = tid & 15, ty = tid >> 4;
  const int row0 = blockIdx.y * 64, col0 = blockIdx.x * 64;
  const int ar = tid >> 2;          // 0..63   A tile row
  const int ac = (tid & 3) << 2;    // 0,4,8,12 A tile k (float4)
  const int br = tid >> 4;          // 0..15   B tile k
  const int bc = (tid & 15) << 2;   // 0..60   B tile col (float4)
  float acc[4][4] = {};
  for (int k0 = 0; k0 < K; k0 += 16) {
    // K is a multiple of 16 and M a multiple of 64 in all calls here.
    float4 a = *(const float4*)(A + (size_t)(row0 + ar) * lda + k0 + ac);
    As[ac+0][ar] = a.x; As[ac+1][ar] = a.y; As[ac+2][ar] = a.z; As[ac+3][ar] = a.w;
    float4 b;
    int bcol = col0 + bc;
    if (bcol + 3 < N) {
      b = *(const float4*)(B + (size_t)(k0 + br) * N + bcol);
    } else {
      float t0 = (bcol+0 < N) ? B[(size_t)(k0+br)*N + bcol+0] : 0.f;
      float t1 = (bcol+1 < N) ? B[(size_t)(k0+br)*N + bcol+1] : 0.f;
      float t2 = (bcol+2 < N) ? B[(size_t)(k0+br)*N + bcol+2] : 0.f;
      float t3 = (bcol+3 < N) ? B[(size_t)(k0+br)*N + bcol+3] : 0.f;
      b = make_float4(t0,t1,t2,t3);
    }
    *(float4*)&Bs[br][bc] = b;
    __syncthreads();
    #pragma unroll
    for (int k = 0; k < 16; ++k) {
      float av[4], bv[4];
      #pragma unroll
      for (int i=0;i<4;i++) av[i] = As[k][(ty<<2)+i];
      #pragma unroll
      for (int j=0;j<4;j++) bv[j] = Bs[k][(tx<<2)+j];
      #pragma unroll
      for (int i=0;i<4;i++)
        #pragma unroll
        for (int j=0;j<4;j++) acc[i][j] = fmaf(av[i], bv[j], acc[i][j]);
    }
    __syncthreads();
  }
  #pragma unroll
  for (int i=0;i<4;i++){
    int r = row0 + (ty<<2) + i;
    if (r >= M) continue;
    #pragma unroll
    for (int j=0;j<4;j++){
      int c = col0 + (tx<<2) + j;
      if (c < N) {
        float v = acc[i][j];
        if (bias) v += bias[c];
        if (act == 1) v = (v > 20.f) ? v : log1pf(__expf(v));
        C[(size_t)r*N + c] = v;
      }
    }
  }
}

// In-place LayerNorm over rows of h[NTOK][D_MODEL]
__global__ __launch_bounds__(256)
void ln_k(float* __restrict__ h, const float* __restrict__ gamma, const float* __restrict__ beta)
{
  const int row = blockIdx.x;
  float* p = h + (size_t)row * D_MODEL;
  float s = 0.f, s2 = 0.f;
  for (int i = threadIdx.x; i < D_MODEL; i += 256) { float v = p[i]; s += v; s2 += v*v; }
  #pragma unroll
  for (int off = 32; off; off >>= 1) { s += __shfl_down(s, off, 64); s2 += __shfl_down(s2, off, 64); }
  __shared__ float ss[4], ss2[4];
  __shared__ float smu, sinv;
  const int wid = threadIdx.x >> 6;
  if ((threadIdx.x & 63) == 0) { ss[wid] = s; ss2[wid] = s2; }
  __syncthreads();
  if (threadIdx.x == 0) {
    float S = ss[0]+ss[1]+ss[2]+ss[3];
    float S2 = ss2[0]+ss2[1]+ss2[2]+ss2[3];
    float mu = S * (1.f / D_MODEL);
    float var = S2 * (1.f / D_MODEL) - mu * mu;
    smu = mu; sinv = rsqrtf(var + 1e-5f);
  }
  __syncthreads();
  const float mu = smu, inv = sinv;
  for (int i = threadIdx.x; i < D_MODEL; i += 256)
    p[i] = (p[i] - mu) * inv * gamma[i] + beta[i];
}

// u[b,t,d] = silu( sum_k conv_w[d,k] * x_branch[b,t+k-3,d] + conv_b[d] )
// x_branch = xz[:, :, :D_INNER] (row stride XZ_N)
__global__ __launch_bounds__(256)
void conv_silu_k(const float* __restrict__ xz, const float* __restrict__ cw,
                 const float* __restrict__ cb, float* __restrict__ u)
{
  const int idx = blockIdx.x * 256 + threadIdx.x;   // (b*T+t)*D_INNER + d
  const int d  = idx & (D_INNER - 1);
  const int bt = idx >> 11;
  const int t  = bt & (SEQ - 1);
  float acc = cb[d];
  const float* base = xz + (size_t)bt * XZ_N + d;   // row (b*T+t), col d
  #pragma unroll
  for (int k = 0; k < D_CONV; ++k) {
    int tt = t + k - (D_CONV - 1);
    if (tt >= 0) acc = fmaf(cw[d*D_CONV + k], base[(ptrdiff_t)(k - (D_CONV-1)) * XZ_N], acc);
  }
  u[idx] = siluf(acc);
}

// Selective scan: one thread per (b,d) channel; 16-state in registers.
// y (written in place over u): y = (scan_y + u*D_skip) * silu(z)
__global__ __launch_bounds__(256)
void scan_k(const float* __restrict__ dtb, float* __restrict__ u,
            const float* __restrict__ xz, const float* __restrict__ proj,
            const float* __restrict__ A_log, const float* __restrict__ D_skip,
            const float* __restrict__ h0, float* __restrict__ outH)
{
  const int b = blockIdx.x >> 3;                    // 8 blocks of 256 d's per batch
  const int d = ((blockIdx.x & 7) << 8) + threadIdx.x;
  float A[D_STATE], h[D_STATE];
  #pragma unroll
  for (int n = 0; n < D_STATE; ++n) {
    A[n] = -__expf(A_log[d*D_STATE + n]);
    h[n] = h0[((size_t)b*D_INNER + d)*D_STATE + n];
  }
  const float Ds = D_skip[d];
  __shared__ float BC[32];
  const size_t rowbase = (size_t)b * SEQ;
  for (int t = 0; t < SEQ; ++t) {
    __syncthreads();
    if (threadIdx.x < 32) BC[threadIdx.x] = proj[(rowbase + t)*PROJ_N + threadIdx.x];
    __syncthreads();
    const float dtv = dtb[(rowbase + t)*D_INNER + d];
    const float uv  = u  [(rowbase + t)*D_INNER + d];
    const float zv  = xz [(rowbase + t)*XZ_N + D_INNER + d];
    float y = 0.f;
    #pragma unroll
    for (int n = 0; n < D_STATE; ++n) {
      float dA = __expf(dtv * A[n]);
      h[n] = fmaf(dA, h[n], dtv * BC[n] * uv);
      y = fmaf(h[n], BC[16 + n], y);
    }
    y = fmaf(uv, Ds, y);
    y *= siluf(zv);
    u[(rowbase + t)*D_INNER + d] = y;
  }
  #pragma unroll
  for (int n = 0; n < D_STATE; ++n)
    outH[((size_t)b*D_INNER + d)*D_STATE + n] = h[n];
}

extern "C" void kernel_launch(void* const* d_in, const int* in_sizes, int n_in,
                              void* d_out, int out_size, void* d_ws, size_t ws_size,
                              hipStream_t stream) {
  const float* x          = (const float*)d_in[0];
  const float* h0         = (const float*)d_in[1];
  const float* W_in_wrap  = (const float*)d_in[2];
  const float* b_in_wrap  = (const float*)d_in[3];
  const float* ln_g       = (const float*)d_in[4];
  const float* ln_b       = (const float*)d_in[5];
  const float* W_in       = (const float*)d_in[6];
  const float* conv_w     = (const float*)d_in[7];
  const float* conv_b     = (const float*)d_in[8];
  const float* W_x        = (const float*)d_in[9];
  const float* W_dt       = (const float*)d_in[10];
  const float* b_dt       = (const float*)d_in[11];
  const float* A_log      = (const float*)d_in[12];
  const float* D_skip     = (const float*)d_in[13];
  const float* W_out      = (const float*)d_in[14];
  const float* W_out_wrap = (const float*)d_in[15];
  const float* b_out_wrap = (const float*)d_in[16];

  float* out  = (float*)d_out;                       // (B,T,OUT_DIM)
  float* outH = out + (size_t)NTOK * OUT_DIM;        // (B,D_INNER,D_STATE)

  // Workspace layout (bytes): total ~90 MB
  char* ws = (char*)d_ws;
  float* hbuf = (float*)(ws);                        //  8 MB  h (NTOK x D_MODEL); reused as tmp later
  float* xz   = (float*)(ws + ((size_t) 8 << 20));   // 32 MB  (NTOK x XZ_N)
  float* u    = (float*)(ws + ((size_t)40 << 20));   // 16 MB  (NTOK x D_INNER); y written in place
  float* proj = (float*)(ws + ((size_t)56 << 20));   // 16.25 MB (NTOK x PROJ_N)
  float* dtb  = (float*)(ws + ((size_t)74 << 20));   // 16 MB  (NTOK x D_INNER)
  float* tmp  = hbuf;                                // reuse after xz GEMM

  dim3 blk(256);
  // 1) h = x @ W_in_wrap + b_in_wrap
  gemm_f32<<<dim3(D_MODEL/64, NTOK/64), blk, 0, stream>>>(x, W_in_wrap, b_in_wrap, hbuf,
                                                          NTOK, D_MODEL, IN_DIM, IN_DIM, 0);
  // 2) LayerNorm in place
  ln_k<<<dim3(NTOK), blk, 0, stream>>>(hbuf, ln_g, ln_b);
  // 3) xz = h @ W_in
  gemm_f32<<<dim3(XZ_N/64, NTOK/64), blk, 0, stream>>>(hbuf, W_in, nullptr, xz,
                                                       NTOK, XZ_N, D_MODEL, D_MODEL, 0);
  // 4) u = silu(causal depthwise conv(x_branch) + conv_b)
  conv_silu_k<<<dim3(NTOK*D_INNER/256), blk, 0, stream>>>(xz, conv_w, conv_b, u);
  // 5) proj = u @ W_x   (N=2080: B_in | C_in | gate)
  gemm_f32<<<dim3((PROJ_N+63)/64, NTOK/64), blk, 0, stream>>>(u, W_x, nullptr, proj,
                                                              NTOK, PROJ_N, D_INNER, D_INNER, 0);
  // 6) dt = softplus(proj[:,32:] @ W_dt + b_dt)
  gemm_f32<<<dim3(D_INNER/64, NTOK/64), blk, 0, stream>>>(proj + 2*D_STATE, W_dt, b_dt, dtb,
                                                          NTOK, D_INNER, D_INNER, PROJ_N, 1);
  // 7) selective scan -> y (in place over u), final state -> outH
  scan_k<<<dim3(BATCH * (D_INNER/256)), blk, 0, stream>>>(dtb, u, xz, proj, A_log, D_skip, h0, outH);
  // 8) tmp = y @ W_out
  gemm_f32<<<dim3(D_MODEL/64, NTOK/64), blk, 0, stream>>>(u, W_out, nullptr, tmp,
                                                          NTOK, D_MODEL, D_INNER, D_INNER, 0);
  // 9) out = tmp @ W_out_wrap + b_out_wrap
  gemm_f32<<<dim3(OUT_DIM/64, NTOK/64), blk, 0, stream>>>(tmp, W_out_wrap, b_out_wrap, out,
                                                          NTOK, OUT_DIM, D_MODEL, D_MODEL, 0);
}

// Round 2
// 1160.703 us; speedup vs baseline: 1.9038x; 1.9038x over previous
//
#include <hip/hip_runtime.h>
#include <cstddef>
#include <cstdint>

#define D_MODEL 1024
#define D_STATE 16
#define D_CONV 4
#define D_INNER 2048
#define IN_DIM 256
#define OUT_DIM 256
#define BATCH 2
#define SEQ 1024
#define NTOK (BATCH*SEQ)
#define XZ_N (2*D_INNER)             // 4096
#define PROJ_N (2*D_STATE + D_INNER) // 2080
#define CHUNK 64
#define NCHUNK (SEQ/CHUNK)           // 16

__device__ __forceinline__ float siluf(float x){ return x / (1.f + __expf(-x)); }

// C[M,N] = act(A[M,K] (row stride lda) * B[K,N] + bias); act: 0=none, 1=softplus
__global__ __launch_bounds__(256)
void gemm_f32(const float* __restrict__ A, const float* __restrict__ B,
              const float* __restrict__ bias, float* __restrict__ C,
              int M, int N, int K, int lda, int act)
{
  __shared__ float As[16][64];   // [k][m]
  __shared__ float Bs[16][64];   // [k][n]
  const int tid = threadIdx.x;
  const int tx = tid & 15, ty = tid >> 4;
  const int row0 = blockIdx.y * 64, col0 = blockIdx.x * 64;
  const int ar = tid >> 2;          // 0..63   A tile row
  const int ac = (tid & 3) << 2;    // 0,4,8,12 A tile k (float4)
  const int br = tid >> 4;          // 0..15   B tile k
  const int bc = (tid & 15) << 2;   // 0..60   B tile col (float4)
  float acc[4][4] = {};
  for (int k0 = 0; k0 < K; k0 += 16) {
    float4 a = *(const float4*)(A + (size_t)(row0 + ar) * lda + k0 + ac);
    As[ac+0][ar] = a.x; As[ac+1][ar] = a.y; As[ac+2][ar] = a.z; As[ac+3][ar] = a.w;
    float4 b;
    int bcol = col0 + bc;
    if (bcol + 3 < N) {
      b = *(const float4*)(B + (size_t)(k0 + br) * N + bcol);
    } else {
      float t0 = (bcol+0 < N) ? B[(size_t)(k0+br)*N + bcol+0] : 0.f;
      float t1 = (bcol+1 < N) ? B[(size_t)(k0+br)*N + bcol+1] : 0.f;
      float t2 = (bcol+2 < N) ? B[(size_t)(k0+br)*N + bcol+2] : 0.f;
      float t3 = (bcol+3 < N) ? B[(size_t)(k0+br)*N + bcol+3] : 0.f;
      b = make_float4(t0,t1,t2,t3);
    }
    *(float4*)&Bs[br][bc] = b;
    __syncthreads();
    #pragma unroll
    for (int k = 0; k < 16; ++k) {
      float av[4], bv[4];
      #pragma unroll
      for (int i=0;i<4;i++) av[i] = As[k][(ty<<2)+i];
      #pragma unroll
      for (int j=0;j<4;j++) bv[j] = Bs[k][(tx<<2)+j];
      #pragma unroll
      for (int i=0;i<4;i++)
        #pragma unroll
        for (int j=0;j<4;j++) acc[i][j] = fmaf(av[i], bv[j], acc[i][j]);
    }
    __syncthreads();
  }
  #pragma unroll
  for (int i=0;i<4;i++){
    int r = row0 + (ty<<2) + i;
    if (r >= M) continue;
    #pragma unroll
    for (int j=0;j<4;j++){
      int c = col0 + (tx<<2) + j;
      if (c < N) {
        float v = acc[i][j];
        if (bias) v += bias[c];
        if (act == 1) v = (v > 20.f) ? v : log1pf(__expf(v));
        C[(size_t)r*N + c] = v;
      }
    }
  }
}

// In-place LayerNorm over rows of h[NTOK][D_MODEL]
__global__ __launch_bounds__(256)
void ln_k(float* __restrict__ h, const float* __restrict__ gamma, const float* __restrict__ beta)
{
  const int row = blockIdx.x;
  float* p = h + (size_t)row * D_MODEL;
  float s = 0.f, s2 = 0.f;
  for (int i = threadIdx.x; i < D_MODEL; i += 256) { float v = p[i]; s += v; s2 += v*v; }
  #pragma unroll
  for (int off = 32; off; off >>= 1) { s += __shfl_down(s, off, 64); s2 += __shfl_down(s2, off, 64); }
  __shared__ float ss[4], ss2[4];
  __shared__ float smu, sinv;
  const int wid = threadIdx.x >> 6;
  if ((threadIdx.x & 63) == 0) { ss[wid] = s; ss2[wid] = s2; }
  __syncthreads();
  if (threadIdx.x == 0) {
    float S = ss[0]+ss[1]+ss[2]+ss[3];
    float S2 = ss2[0]+ss2[1]+ss2[2]+ss2[3];
    float mu = S * (1.f / D_MODEL);
    float var = S2 * (1.f / D_MODEL) - mu * mu;
    smu = mu; sinv = rsqrtf(var + 1e-5f);
  }
  __syncthreads();
  const float mu = smu, inv = sinv;
  for (int i = threadIdx.x; i < D_MODEL; i += 256)
    p[i] = (p[i] - mu) * inv * gamma[i] + beta[i];
}

// u[b,t,d] = silu( sum_k conv_w[d,k] * x_branch[b,t+k-3,d] + conv_b[d] )
__global__ __launch_bounds__(256)
void conv_silu_k(const float* __restrict__ xz, const float* __restrict__ cw,
                 const float* __restrict__ cb, float* __restrict__ u)
{
  const int idx = blockIdx.x * 256 + threadIdx.x;   // (b*T+t)*D_INNER + d
  const int d  = idx & (D_INNER - 1);
  const int bt = idx >> 11;
  const int t  = bt & (SEQ - 1);
  float acc = cb[d];
  const float* base = xz + (size_t)bt * XZ_N + d;
  #pragma unroll
  for (int k = 0; k < D_CONV; ++k) {
    int tt = t + k - (D_CONV - 1);
    if (tt >= 0) acc = fmaf(cw[d*D_CONV + k], base[(ptrdiff_t)(k - (D_CONV-1)) * XZ_N], acc);
  }
  u[idx] = siluf(acc);
}

// ---- chunk-parallel selective scan ----
// summ layout: [B][NCHUNK][32][D_INNER]; slots 0..15 = prodDA (pass1) -> chunk-start h (pass2),
//              slots 16..31 = local end-state from h=0.

// Pass 1: per (b,chunk,d): local scan from h=0; emit summary.
__global__ __launch_bounds__(256)
void scan_p1(const float* __restrict__ dtb, const float* __restrict__ u,
             const float* __restrict__ proj, const float* __restrict__ A_log,
             float* __restrict__ summ)
{
  const int bid = blockIdx.x;                 // b*128 + c*8 + blk
  const int b = bid >> 7;
  const int c = (bid >> 3) & (NCHUNK - 1);
  const int d = ((bid & 7) << 8) + threadIdx.x;
  float A[D_STATE], hl[D_STATE];
  #pragma unroll
  for (int n = 0; n < D_STATE; ++n) { A[n] = -__expf(A_log[d*D_STATE + n]); hl[n] = 0.f; }
  float dtsum = 0.f;
  const size_t row0 = (size_t)b * SEQ + (size_t)c * CHUNK;
  for (int t = 0; t < CHUNK; ++t) {
    const size_t r = row0 + t;
    const float dtv = dtb[r*D_INNER + d];
    const float uv  = u  [r*D_INNER + d];
    const float du = dtv * uv;
    dtsum += dtv;
    const float* Bp = proj + r*PROJ_N;        // wave-uniform -> scalar broadcast
    #pragma unroll
    for (int n = 0; n < D_STATE; ++n) {
      float dA = __expf(dtv * A[n]);
      hl[n] = fmaf(dA, hl[n], du * Bp[n]);
    }
  }
  float* s = summ + (((size_t)b*NCHUNK + c)*32)*D_INNER + d;
  #pragma unroll
  for (int n = 0; n < D_STATE; ++n) {
    s[(size_t)n*D_INNER]      = __expf(A[n] * dtsum);   // prod of dA over chunk
    s[(size_t)(16+n)*D_INNER] = hl[n];
  }
}

// Pass 2: per (b,d): stitch 16 chunks sequentially; overwrite prodDA slot with
// the chunk-START state; write final hT.
__global__ __launch_bounds__(256)
void scan_p2(float* __restrict__ summ, const float* __restrict__ h0,
             float* __restrict__ outH)
{
  const int b = blockIdx.x >> 3;
  const int d = ((blockIdx.x & 7) << 8) + threadIdx.x;
  float h[D_STATE];
  #pragma unroll
  for (int n = 0; n < D_STATE; ++n) h[n] = h0[((size_t)b*D_INNER + d)*D_STATE + n];
  for (int c = 0; c < NCHUNK; ++c) {
    float* s = summ + (((size_t)b*NCHUNK + c)*32)*D_INNER + d;
    #pragma unroll
    for (int n = 0; n < D_STATE; ++n) {
      float p = s[(size_t)n*D_INNER];
      float l = s[(size_t)(16+n)*D_INNER];
      s[(size_t)n*D_INNER] = h[n];            // start state for chunk c
      h[n] = fmaf(p, h[n], l);
    }
  }
  #pragma unroll
  for (int n = 0; n < D_STATE; ++n)
    outH[((size_t)b*D_INNER + d)*D_STATE + n] = h[n];
}

// Pass 3: per (b,chunk,d): rerun local scan from true start state; emit y
// (fused +u*D_skip and *silu(z)), in place over u.
__global__ __launch_bounds__(256)
void scan_p3(const float* __restrict__ dtb, float* __restrict__ u,
             const float* __restrict__ xz, const float* __restrict__ proj,
             const float* __restrict__ A_log, const float* __restrict__ D_skip,
             const float* __restrict__ summ)
{
  const int bid = blockIdx.x;
  const int b = bid >> 7;
  const int c = (bid >> 3) & (NCHUNK - 1);
  const int d = ((bid & 7) << 8) + threadIdx.x;
  float A[D_STATE], h[D_STATE];
  const float* s = summ + (((size_t)b*NCHUNK + c)*32)*D_INNER + d;
  #pragma unroll
  for (int n = 0; n < D_STATE; ++n) {
    A[n] = -__expf(A_log[d*D_STATE + n]);
    h[n] = s[(size_t)n*D_INNER];
  }
  const float Ds = D_skip[d];
  const size_t row0 = (size_t)b * SEQ + (size_t)c * CHUNK;
  for (int t = 0; t < CHUNK; ++t) {
    const size_t r = row0 + t;
    const float dtv = dtb[r*D_INNER + d];
    const float uv  = u  [r*D_INNER + d];
    const float zv  = xz [r*XZ_N + D_INNER + d];
    const float du = dtv * uv;
    const float* Bp = proj + r*PROJ_N;
    float y = 0.f;
    #pragma unroll
    for (int n = 0; n < D_STATE; ++n) {
      float dA = __expf(dtv * A[n]);
      h[n] = fmaf(dA, h[n], du * Bp[n]);
      y = fmaf(h[n], Bp[16+n], y);
    }
    y = fmaf(uv, Ds, y);
    u[r*D_INNER + d] = y * siluf(zv);
  }
}

extern "C" void kernel_launch(void* const* d_in, const int* in_sizes, int n_in,
                              void* d_out, int out_size, void* d_ws, size_t ws_size,
                              hipStream_t stream) {
  const float* x          = (const float*)d_in[0];
  const float* h0         = (const float*)d_in[1];
  const float* W_in_wrap  = (const float*)d_in[2];
  const float* b_in_wrap  = (const float*)d_in[3];
  const float* ln_g       = (const float*)d_in[4];
  const float* ln_b       = (const float*)d_in[5];
  const float* W_in       = (const float*)d_in[6];
  const float* conv_w     = (const float*)d_in[7];
  const float* conv_b     = (const float*)d_in[8];
  const float* W_x        = (const float*)d_in[9];
  const float* W_dt       = (const float*)d_in[10];
  const float* b_dt       = (const float*)d_in[11];
  const float* A_log      = (const float*)d_in[12];
  const float* D_skip     = (const float*)d_in[13];
  const float* W_out      = (const float*)d_in[14];
  const float* W_out_wrap = (const float*)d_in[15];
  const float* b_out_wrap = (const float*)d_in[16];

  float* out  = (float*)d_out;                       // (B,T,OUT_DIM)
  float* outH = out + (size_t)NTOK * OUT_DIM;        // (B,D_INNER,D_STATE)

  char* ws = (char*)d_ws;
  float* hbuf = (float*)(ws);                        //  8 MB  h; scan summaries; tmp
  float* xz   = (float*)(ws + ((size_t) 8 << 20));   // 32 MB  (NTOK x XZ_N)
  float* u    = (float*)(ws + ((size_t)40 << 20));   // 16 MB  (NTOK x D_INNER)
  float* proj = (float*)(ws + ((size_t)56 << 20));   // 16.25 MB (NTOK x PROJ_N)
  float* dtb  = (float*)(ws + ((size_t)74 << 20));   // 16 MB  (NTOK x D_INNER)
  float* summ = hbuf;                                // 8 MB, dead interval of hbuf
  float* tmp  = hbuf;

  dim3 blk(256);
  // 1) h = x @ W_in_wrap + b_in_wrap
  gemm_f32<<<dim3(D_MODEL/64, NTOK/64), blk, 0, stream>>>(x, W_in_wrap, b_in_wrap, hbuf,
                                                          NTOK, D_MODEL, IN_DIM, IN_DIM, 0);
  // 2) LayerNorm in place
  ln_k<<<dim3(NTOK), blk, 0, stream>>>(hbuf, ln_g, ln_b);
  // 3) xz = h @ W_in
  gemm_f32<<<dim3(XZ_N/64, NTOK/64), blk, 0, stream>>>(hbuf, W_in, nullptr, xz,
                                                       NTOK, XZ_N, D_MODEL, D_MODEL, 0);
  // 4) u = silu(causal depthwise conv(x_branch) + conv_b)
  conv_silu_k<<<dim3(NTOK*D_INNER/256), blk, 0, stream>>>(xz, conv_w, conv_b, u);
  // 5) proj = u @ W_x
  gemm_f32<<<dim3((PROJ_N+63)/64, NTOK/64), blk, 0, stream>>>(u, W_x, nullptr, proj,
                                                              NTOK, PROJ_N, D_INNER, D_INNER, 0);
  // 6) dt = softplus(proj[:,32:] @ W_dt + b_dt)
  gemm_f32<<<dim3(D_INNER/64, NTOK/64), blk, 0, stream>>>(proj + 2*D_STATE, W_dt, b_dt, dtb,
                                                          NTOK, D_INNER, D_INNER, PROJ_N, 1);
  // 7) chunk-parallel scan
  scan_p1<<<dim3(BATCH*NCHUNK*(D_INNER/256)), blk, 0, stream>>>(dtb, u, proj, A_log, summ);
  scan_p2<<<dim3(BATCH*(D_INNER/256)), blk, 0, stream>>>(summ, h0, outH);
  scan_p3<<<dim3(BATCH*NCHUNK*(D_INNER/256)), blk, 0, stream>>>(dtb, u, xz, proj, A_log, D_skip, summ);
  // 8) tmp = y @ W_out
  gemm_f32<<<dim3(D_MODEL/64, NTOK/64), blk, 0, stream>>>(u, W_out, nullptr, tmp,
                                                          NTOK, D_MODEL, D_INNER, D_INNER, 0);
  // 9) out = tmp @ W_out_wrap + b_out_wrap
  gemm_f32<<<dim3(OUT_DIM/64, NTOK/64), blk, 0, stream>>>(tmp, W_out_wrap, b_out_wrap, out,
                                                          NTOK, OUT_DIM, D_MODEL, D_MODEL, 0);
}

// Round 3
// 430.648 us; speedup vs baseline: 5.1312x; 2.6952x over previous
//
#include <hip/hip_runtime.h>
#include <cstddef>
#include <cstdint>

#define D_MODEL 1024
#define D_STATE 16
#define D_CONV 4
#define D_INNER 2048
#define IN_DIM 256
#define OUT_DIM 256
#define BATCH 2
#define SEQ 1024
#define NTOK (BATCH*SEQ)
#define PROJ_N (2*D_STATE + D_INNER) // 2080
#define CHUNK 64
#define NCHUNK (SEQ/CHUNK)           // 16

typedef __attribute__((ext_vector_type(8))) short bf16x8;
typedef __attribute__((ext_vector_type(4))) float f32x4;

__device__ __forceinline__ float siluf(float x){ return x / (1.f + __expf(-x)); }

__device__ __forceinline__ unsigned short f2bf(float f) {
  uint32_t x = __float_as_uint(f);
  uint32_t r = x + 0x7fffu + ((x >> 16) & 1u);
  return (unsigned short)(r >> 16);
}
__device__ __forceinline__ float bf2f(unsigned short u) {
  return __uint_as_float(((uint32_t)u) << 16);
}

__device__ __forceinline__ void gload16(const void* g, void* l) {
  __builtin_amdgcn_global_load_lds((const __attribute__((address_space(1))) void*)g,
                                   (__attribute__((address_space(3))) void*)l, 16, 0, 0);
}

// ---------------- fp32 fallback GEMM (small first GEMM only) ----------------
__global__ __launch_bounds__(256)
void gemm_f32(const float* __restrict__ A, const float* __restrict__ B,
              const float* __restrict__ bias, float* __restrict__ C,
              int M, int N, int K, int lda, int act)
{
  __shared__ float As[16][64];
  __shared__ float Bs[16][64];
  const int tid = threadIdx.x;
  const int tx = tid & 15, ty = tid >> 4;
  const int row0 = blockIdx.y * 64, col0 = blockIdx.x * 64;
  const int ar = tid >> 2;
  const int ac = (tid & 3) << 2;
  const int br = tid >> 4;
  const int bc = (tid & 15) << 2;
  float acc[4][4] = {};
  for (int k0 = 0; k0 < K; k0 += 16) {
    float4 a = *(const float4*)(A + (size_t)(row0 + ar) * lda + k0 + ac);
    As[ac+0][ar] = a.x; As[ac+1][ar] = a.y; As[ac+2][ar] = a.z; As[ac+3][ar] = a.w;
    float4 b = *(const float4*)(B + (size_t)(k0 + br) * N + col0 + bc);
    *(float4*)&Bs[br][bc] = b;
    __syncthreads();
    #pragma unroll
    for (int k = 0; k < 16; ++k) {
      float av[4], bv[4];
      #pragma unroll
      for (int i=0;i<4;i++) av[i] = As[k][(ty<<2)+i];
      #pragma unroll
      for (int j=0;j<4;j++) bv[j] = Bs[k][(tx<<2)+j];
      #pragma unroll
      for (int i=0;i<4;i++)
        #pragma unroll
        for (int j=0;j<4;j++) acc[i][j] = fmaf(av[i], bv[j], acc[i][j]);
    }
    __syncthreads();
  }
  #pragma unroll
  for (int i=0;i<4;i++){
    int r = row0 + (ty<<2) + i;
    #pragma unroll
    for (int j=0;j<4;j++){
      int c = col0 + (tx<<2) + j;
      float v = acc[i][j];
      if (bias) v += bias[c];
      C[(size_t)r*N + c] = v;
    }
  }
}

// ---------------- transpose + cast fp32 [R][C] -> bf16 [C][R] ----------------
__global__ __launch_bounds__(256)
void transpose_cast(const float* __restrict__ in, unsigned short* __restrict__ out,
                    int R, int C)
{
  __shared__ float tile[32][33];
  const int bc = blockIdx.x * 32, br = blockIdx.y * 32;
  const int tx = threadIdx.x & 31, ty = threadIdx.x >> 5;  // ty 0..7
  #pragma unroll
  for (int i = 0; i < 4; ++i) {
    int r = ty + i*8;
    tile[r][tx] = in[(size_t)(br + r)*C + bc + tx];
  }
  __syncthreads();
  #pragma unroll
  for (int i = 0; i < 4; ++i) {
    int r = ty + i*8;
    out[(size_t)(bc + r)*R + br + tx] = f2bf(tile[tx][r]);
  }
}

// ---------------- bf16 MFMA GEMM: 128x128x32 tile, 4 waves ----------------
// B is pre-transposed: B[N][K] row-major (row n, stride K).
// modes: 0 f32 out (+bias); 1 softplus(v+bias) f32; 2 bf16 out;
//        3 split xz -> out0=xb fp32 [M][2048] (c<2048), out1=zb fp32 (c>=2048);
//        4 proj -> out0=BC fp32 [M][32] (c<32), out1=g bf16 [M][2048] (c>=32)
__global__ __launch_bounds__(256)
void gemm_bf16(const unsigned short* __restrict__ A, const unsigned short* __restrict__ B,
               int M, int N, int K, int lda,
               const float* __restrict__ bias,
               void* __restrict__ out0, void* __restrict__ out1, int mode)
{
  __shared__ __align__(1024) unsigned short As[128*32];
  __shared__ __align__(1024) unsigned short Bs[128*32];
  const int tid = threadIdx.x;
  const int lane = tid & 63, w = tid >> 6;
  const int row0 = blockIdx.y * 128, col0 = blockIdx.x * 128;
  const int wr = (w >> 1) * 64, wc = (w & 1) * 64;
  const int lrq = lane >> 2;     // row within 16-row staging group
  const int lg  = lane & 3;      // dest granule
  const int l15 = lane & 15, lg4 = lane >> 4;

  f32x4 acc[4][4];
  #pragma unroll
  for (int i=0;i<4;i++)
    #pragma unroll
    for (int j=0;j<4;j++) acc[i][j] = (f32x4){0.f,0.f,0.f,0.f};

  for (int k0 = 0; k0 < K; k0 += 32) {
    #pragma unroll
    for (int s = 0; s < 2; ++s) {
      const int base = w*32 + s*16;
      const int lr = base + lrq;
      const int gs = lg ^ ((lr >> 1) & 3);   // swizzled source granule
      gload16(A + (size_t)(row0 + lr)*lda + k0 + gs*8, &As[base*32]);
      gload16(B + (size_t)(col0 + lr)*K  + k0 + gs*8, &Bs[base*32]);
    }
    __syncthreads();
    bf16x8 af[4], bfr[4];
    #pragma unroll
    for (int mi=0;mi<4;mi++){
      const int r = wr + mi*16 + l15;
      const int slot = lg4 ^ ((r >> 1) & 3);
      af[mi] = *(const bf16x8*)&As[r*32 + slot*8];
    }
    #pragma unroll
    for (int ni=0;ni<4;ni++){
      const int r = wc + ni*16 + l15;
      const int slot = lg4 ^ ((r >> 1) & 3);
      bfr[ni] = *(const bf16x8*)&Bs[r*32 + slot*8];
    }
    #pragma unroll
    for (int mi=0;mi<4;mi++)
      #pragma unroll
      for (int ni=0;ni<4;ni++)
        acc[mi][ni] = __builtin_amdgcn_mfma_f32_16x16x32_bf16(af[mi], bfr[ni], acc[mi][ni], 0, 0, 0);
    __syncthreads();
  }

  #pragma unroll
  for (int mi=0;mi<4;mi++){
    const int rb = row0 + wr + mi*16 + lg4*4;
    #pragma unroll
    for (int ni=0;ni<4;ni++){
      const int c = col0 + wc + ni*16 + l15;
      #pragma unroll
      for (int q=0;q<4;q++){
        const int r = rb + q;
        float v = acc[mi][ni][q];
        if (mode == 0) {
          if (c < N) ((float*)out0)[(size_t)r*N + c] = bias ? v + bias[c] : v;
        } else if (mode == 1) {
          if (c < N) { v += bias[c]; v = (v > 20.f) ? v : log1pf(__expf(v));
                       ((float*)out0)[(size_t)r*N + c] = v; }
        } else if (mode == 2) {
          if (c < N) ((unsigned short*)out0)[(size_t)r*N + c] = f2bf(v);
        } else if (mode == 3) {
          if (c < 2048) ((float*)out0)[(size_t)r*2048 + c] = v;
          else          ((float*)out1)[(size_t)r*2048 + (c - 2048)] = v;
        } else {
          if (c < 32) ((float*)out0)[(size_t)r*32 + c] = v;
          else if (c < N) ((unsigned short*)out1)[(size_t)r*2048 + (c - 32)] = f2bf(v);
        }
      }
    }
  }
}

// LayerNorm: read fp32 h, write bf16
__global__ __launch_bounds__(256)
void ln_k(const float* __restrict__ h, const float* __restrict__ gamma,
          const float* __restrict__ beta, unsigned short* __restrict__ hb)
{
  const int row = blockIdx.x;
  const float* p = h + (size_t)row * D_MODEL;
  float s = 0.f, s2 = 0.f;
  for (int i = threadIdx.x; i < D_MODEL; i += 256) { float v = p[i]; s += v; s2 += v*v; }
  #pragma unroll
  for (int off = 32; off; off >>= 1) { s += __shfl_down(s, off, 64); s2 += __shfl_down(s2, off, 64); }
  __shared__ float ss[4], ss2[4];
  __shared__ float smu, sinv;
  const int wid = threadIdx.x >> 6;
  if ((threadIdx.x & 63) == 0) { ss[wid] = s; ss2[wid] = s2; }
  __syncthreads();
  if (threadIdx.x == 0) {
    float S = ss[0]+ss[1]+ss[2]+ss[3];
    float S2 = ss2[0]+ss2[1]+ss2[2]+ss2[3];
    float mu = S * (1.f / D_MODEL);
    float var = S2 * (1.f / D_MODEL) - mu * mu;
    smu = mu; sinv = rsqrtf(var + 1e-5f);
  }
  __syncthreads();
  const float mu = smu, inv = sinv;
  unsigned short* q = hb + (size_t)row * D_MODEL;
  for (int i = threadIdx.x; i < D_MODEL; i += 256)
    q[i] = f2bf((p[i] - mu) * inv * gamma[i] + beta[i]);
}

// conv+silu: read xb fp32 [NTOK][2048], write u bf16
__global__ __launch_bounds__(256)
void conv_silu_k(const float* __restrict__ xb, const float* __restrict__ cw,
                 const float* __restrict__ cb, unsigned short* __restrict__ ub)
{
  const int idx = blockIdx.x * 256 + threadIdx.x;
  const int d  = idx & (D_INNER - 1);
  const int bt = idx >> 11;
  const int t  = bt & (SEQ - 1);
  float acc = cb[d];
  const float* base = xb + (size_t)bt * D_INNER + d;
  #pragma unroll
  for (int k = 0; k < D_CONV; ++k) {
    int tt = t + k - (D_CONV - 1);
    if (tt >= 0) acc = fmaf(cw[d*D_CONV + k], base[(ptrdiff_t)(k - (D_CONV-1)) * D_INNER], acc);
  }
  ub[idx] = f2bf(siluf(acc));
}

// ---- chunk-parallel scan; BC compact [NTOK][32] fp32 ----
__global__ __launch_bounds__(256)
void scan_p1(const float* __restrict__ dtb, const unsigned short* __restrict__ ub,
             const float* __restrict__ BC, const float* __restrict__ A_log,
             float* __restrict__ summ)
{
  const int bid = blockIdx.x;
  const int b = bid >> 7;
  const int c = (bid >> 3) & (NCHUNK - 1);
  const int d = ((bid & 7) << 8) + threadIdx.x;
  float A[D_STATE], hl[D_STATE];
  #pragma unroll
  for (int n = 0; n < D_STATE; ++n) { A[n] = -__expf(A_log[d*D_STATE + n]); hl[n] = 0.f; }
  float dtsum = 0.f;
  const size_t row0 = (size_t)b * SEQ + (size_t)c * CHUNK;
  for (int t = 0; t < CHUNK; ++t) {
    const size_t r = row0 + t;
    const float dtv = dtb[r*D_INNER + d];
    const float uv  = bf2f(ub[r*D_INNER + d]);
    const float du = dtv * uv;
    dtsum += dtv;
    const float* Bp = BC + r*32;
    #pragma unroll
    for (int n = 0; n < D_STATE; ++n) {
      float dA = __expf(dtv * A[n]);
      hl[n] = fmaf(dA, hl[n], du * Bp[n]);
    }
  }
  float* s = summ + (((size_t)b*NCHUNK + c)*32)*D_INNER + d;
  #pragma unroll
  for (int n = 0; n < D_STATE; ++n) {
    s[(size_t)n*D_INNER]      = __expf(A[n] * dtsum);
    s[(size_t)(16+n)*D_INNER] = hl[n];
  }
}

__global__ __launch_bounds__(256)
void scan_p2(float* __restrict__ summ, const float* __restrict__ h0,
             float* __restrict__ outH)
{
  const int b = blockIdx.x >> 3;
  const int d = ((blockIdx.x & 7) << 8) + threadIdx.x;
  float h[D_STATE];
  #pragma unroll
  for (int n = 0; n < D_STATE; ++n) h[n] = h0[((size_t)b*D_INNER + d)*D_STATE + n];
  for (int c = 0; c < NCHUNK; ++c) {
    float* s = summ + (((size_t)b*NCHUNK + c)*32)*D_INNER + d;
    #pragma unroll
    for (int n = 0; n < D_STATE; ++n) {
      float p = s[(size_t)n*D_INNER];
      float l = s[(size_t)(16+n)*D_INNER];
      s[(size_t)n*D_INNER] = h[n];
      h[n] = fmaf(p, h[n], l);
    }
  }
  #pragma unroll
  for (int n = 0; n < D_STATE; ++n)
    outH[((size_t)b*D_INNER + d)*D_STATE + n] = h[n];
}

__global__ __launch_bounds__(256)
void scan_p3(const float* __restrict__ dtb, const unsigned short* __restrict__ ub,
             const float* __restrict__ zb, const float* __restrict__ BC,
             const float* __restrict__ A_log, const float* __restrict__ D_skip,
             const float* __restrict__ summ, unsigned short* __restrict__ yb)
{
  const int bid = blockIdx.x;
  const int b = bid >> 7;
  const int c = (bid >> 3) & (NCHUNK - 1);
  const int d = ((bid & 7) << 8) + threadIdx.x;
  float A[D_STATE], h[D_STATE];
  const float* s = summ + (((size_t)b*NCHUNK + c)*32)*D_INNER + d;
  #pragma unroll
  for (int n = 0; n < D_STATE; ++n) {
    A[n] = -__expf(A_log[d*D_STATE + n]);
    h[n] = s[(size_t)n*D_INNER];
  }
  const float Ds = D_skip[d];
  const size_t row0 = (size_t)b * SEQ + (size_t)c * CHUNK;
  for (int t = 0; t < CHUNK; ++t) {
    const size_t r = row0 + t;
    const float dtv = dtb[r*D_INNER + d];
    const float uv  = bf2f(ub[r*D_INNER + d]);
    const float zv  = zb[r*D_INNER + d];
    const float du = dtv * uv;
    const float* Bp = BC + r*32;
    float y = 0.f;
    #pragma unroll
    for (int n = 0; n < D_STATE; ++n) {
      float dA = __expf(dtv * A[n]);
      h[n] = fmaf(dA, h[n], du * Bp[n]);
      y = fmaf(h[n], Bp[16+n], y);
    }
    y = fmaf(uv, Ds, y);
    yb[r*D_INNER + d] = f2bf(y * siluf(zv));
  }
}

extern "C" void kernel_launch(void* const* d_in, const int* in_sizes, int n_in,
                              void* d_out, int out_size, void* d_ws, size_t ws_size,
                              hipStream_t stream) {
  const float* x          = (const float*)d_in[0];
  const float* h0         = (const float*)d_in[1];
  const float* W_in_wrap  = (const float*)d_in[2];
  const float* b_in_wrap  = (const float*)d_in[3];
  const float* ln_g       = (const float*)d_in[4];
  const float* ln_b       = (const float*)d_in[5];
  const float* W_in       = (const float*)d_in[6];
  const float* conv_w     = (const float*)d_in[7];
  const float* conv_b     = (const float*)d_in[8];
  const float* W_x        = (const float*)d_in[9];
  const float* W_dt       = (const float*)d_in[10];
  const float* b_dt       = (const float*)d_in[11];
  const float* A_log      = (const float*)d_in[12];
  const float* D_skip     = (const float*)d_in[13];
  const float* W_out      = (const float*)d_in[14];
  const float* W_out_wrap = (const float*)d_in[15];
  const float* b_out_wrap = (const float*)d_in[16];

  float* out  = (float*)d_out;                       // (B,T,OUT_DIM)
  float* outH = out + (size_t)NTOK * OUT_DIM;        // (B,D_INNER,D_STATE)

  char* ws = (char*)d_ws;
  auto at = [&](size_t kb){ return (void*)(ws + kb*1024); };
  float*          hbuf = (float*)at(0);        // 8 MB fp32 h (then summ)
  float*          summ = hbuf;
  float*          xb   = (float*)at(8192);     // 16 MB fp32 x_branch (then dtb)
  float*          dtb  = xb;
  float*          zb   = (float*)at(24576);    // 16 MB fp32 z
  unsigned short* ub   = (unsigned short*)at(40960);  // 8 MB bf16 u
  unsigned short* gb   = (unsigned short*)at(49152);  // 8 MB bf16 gate (then y)
  unsigned short* yb   = gb;
  unsigned short* hb   = (unsigned short*)at(57344);  // 4 MB bf16 h_ln (then tmp)
  unsigned short* tmpb = hb;
  float*          BC   = (float*)at(61440);    // 256 KB fp32 [NTOK][32]
  unsigned short* WinT = (unsigned short*)at(61696);  // 8 MB   [4096][1024]
  unsigned short* WxT  = (unsigned short*)at(69888);  // 8.5 MB [2176pad][2048]
  unsigned short* WdtT = (unsigned short*)at(78592);  // 8 MB   [2048][2048]
  unsigned short* WoutT= (unsigned short*)at(86784);  // 4 MB   [1024][2048]
  unsigned short* WwrT = (unsigned short*)at(90880);  // 512 KB [256][1024]  (ends 89.25 MB)

  dim3 blk(256);
  // weight transposes (fp32 -> bf16, [R][C] -> [C][R])
  transpose_cast<<<dim3(4096/32, 1024/32), blk, 0, stream>>>(W_in, WinT, 1024, 4096);
  transpose_cast<<<dim3(2080/32, 2048/32), blk, 0, stream>>>(W_x, WxT, 2048, 2080);
  transpose_cast<<<dim3(2048/32, 2048/32), blk, 0, stream>>>(W_dt, WdtT, 2048, 2048);
  transpose_cast<<<dim3(1024/32, 2048/32), blk, 0, stream>>>(W_out, WoutT, 2048, 1024);
  transpose_cast<<<dim3(256/32, 1024/32), blk, 0, stream>>>(W_out_wrap, WwrT, 1024, 256);

  // 1) h = x @ W_in_wrap + b_in_wrap   (fp32, K=256)
  gemm_f32<<<dim3(D_MODEL/64, NTOK/64), blk, 0, stream>>>(x, W_in_wrap, b_in_wrap, hbuf,
                                                          NTOK, D_MODEL, IN_DIM, IN_DIM, 0);
  // 2) LayerNorm -> bf16
  ln_k<<<dim3(NTOK), blk, 0, stream>>>(hbuf, ln_g, ln_b, hb);
  // 3) xz = h @ W_in  -> xb fp32 | zb fp32
  gemm_bf16<<<dim3(4096/128, NTOK/128), blk, 0, stream>>>(hb, WinT, NTOK, 4096, 1024, 1024,
                                                          nullptr, xb, zb, 3);
  // 4) u = silu(conv(xb)) -> bf16
  conv_silu_k<<<dim3(NTOK*D_INNER/256), blk, 0, stream>>>(xb, conv_w, conv_b, ub);
  // 5) proj = u @ W_x -> BC fp32 [.,32] | g bf16 [.,2048]
  gemm_bf16<<<dim3((PROJ_N+127)/128, NTOK/128), blk, 0, stream>>>(ub, WxT, NTOK, PROJ_N, 2048, 2048,
                                                                  nullptr, BC, gb, 4);
  // 6) dt = softplus(g @ W_dt + b_dt) -> fp32 (over xb)
  gemm_bf16<<<dim3(2048/128, NTOK/128), blk, 0, stream>>>(gb, WdtT, NTOK, 2048, 2048, 2048,
                                                          b_dt, dtb, nullptr, 1);
  // 7) chunk-parallel scan
  scan_p1<<<dim3(BATCH*NCHUNK*(D_INNER/256)), blk, 0, stream>>>(dtb, ub, BC, A_log, summ);
  scan_p2<<<dim3(BATCH*(D_INNER/256)), blk, 0, stream>>>(summ, h0, outH);
  scan_p3<<<dim3(BATCH*NCHUNK*(D_INNER/256)), blk, 0, stream>>>(dtb, ub, zb, BC, A_log, D_skip, summ, yb);
  // 8) tmp = y @ W_out -> bf16 (over hb)
  gemm_bf16<<<dim3(1024/128, NTOK/128), blk, 0, stream>>>(yb, WoutT, NTOK, 1024, 2048, 2048,
                                                          nullptr, tmpb, nullptr, 2);
  // 9) out = tmp @ W_out_wrap + b_out_wrap (fp32 out)
  gemm_bf16<<<dim3(256/128, NTOK/128), blk, 0, stream>>>(tmpb, WwrT, NTOK, 256, 1024, 1024,
                                                         b_out_wrap, out, nullptr, 0);
}

// Round 4
// 302.673 us; speedup vs baseline: 7.3008x; 1.4228x over previous
//
#include <hip/hip_runtime.h>
#include <cstddef>
#include <cstdint>

#define D_MODEL 1024
#define D_STATE 16
#define D_CONV 4
#define D_INNER 2048
#define IN_DIM 256
#define OUT_DIM 256
#define BATCH 2
#define SEQ 1024
#define NTOK (BATCH*SEQ)
#define PROJ_N (2*D_STATE + D_INNER) // 2080
#define CHUNK 64
#define NCHUNK (SEQ/CHUNK)           // 16

typedef __attribute__((ext_vector_type(8))) short bf16x8;
typedef __attribute__((ext_vector_type(4))) float f32x4;

__device__ __forceinline__ float siluf(float x){ return x / (1.f + __expf(-x)); }

__device__ __forceinline__ unsigned short f2bf(float f) {
  uint32_t x = __float_as_uint(f);
  uint32_t r = x + 0x7fffu + ((x >> 16) & 1u);
  return (unsigned short)(r >> 16);
}
__device__ __forceinline__ float bf2f(unsigned short u) {
  return __uint_as_float(((uint32_t)u) << 16);
}

__device__ __forceinline__ void gload16(const void* g, void* l) {
  __builtin_amdgcn_global_load_lds((const __attribute__((address_space(1))) void*)g,
                                   (__attribute__((address_space(3))) void*)l, 16, 0, 0);
}

// ---------------- transpose + cast fp32 [R][C] -> bf16 [C][R] ----------------
__global__ __launch_bounds__(256)
void transpose_cast(const float* __restrict__ in, unsigned short* __restrict__ out,
                    int R, int C)
{
  __shared__ float tile[32][33];
  const int bc = blockIdx.x * 32, br = blockIdx.y * 32;
  const int tx = threadIdx.x & 31, ty = threadIdx.x >> 5;  // ty 0..7
  #pragma unroll
  for (int i = 0; i < 4; ++i) {
    int r = ty + i*8;
    tile[r][tx] = in[(size_t)(br + r)*C + bc + tx];
  }
  __syncthreads();
  #pragma unroll
  for (int i = 0; i < 4; ++i) {
    int r = ty + i*8;
    out[(size_t)(bc + r)*R + br + tx] = f2bf(tile[tx][r]);
  }
}

// elementwise fp32 -> bf16 (float4 granularity)
__global__ __launch_bounds__(256)
void cast_bf16_k(const float* __restrict__ in, unsigned short* __restrict__ out, int n4)
{
  int i = blockIdx.x * 256 + threadIdx.x;
  if (i < n4) {
    float4 v = ((const float4*)in)[i];
    ushort4 o;
    o.x = f2bf(v.x); o.y = f2bf(v.y); o.z = f2bf(v.z); o.w = f2bf(v.w);
    ((ushort4*)out)[i] = o;
  }
}

// ---------------- bf16 MFMA GEMM: BM=128 x BN tile, 4 waves, depth-2 pipeline --
// B pre-transposed: B[N][K] row-major. 3-buffer LDS, raw s_barrier, counted vmcnt.
// MODE: 0 f32 out (+bias); 1 softplus(v+bias) f32; 2 bf16 out;
//       3 split xz -> out0=xb fp32 [M][2048] (c<2048), out1=zb fp32;
//       4 proj -> out0=BC fp32 [M][32] (c<32), out1=g bf16 [M][2048]
template<int BN, int MODE>
__global__ __launch_bounds__(256)
void gemm_bf16(const unsigned short* __restrict__ A, const unsigned short* __restrict__ B,
               int M, int N, int K, int lda, int ldb,
               const float* __restrict__ bias,
               void* __restrict__ out0, void* __restrict__ out1)
{
  constexpr int BM = 128;
  constexpr int WN = BN / 2;            // wave tile 64 x WN
  constexpr int NREP = WN / 16;
  constexpr int ROWS = BM + BN;
  constexpr int G = ROWS / 16;          // 16-row staging groups
  constexpr int IPW = G / 4;            // gload16 issues per wave per stage
  __shared__ __align__(1024) unsigned short S[3][ROWS*32];

  const int tid = threadIdx.x;
  const int lane = tid & 63, w = tid >> 6;
  const int row0 = blockIdx.y * BM, col0 = blockIdx.x * BN;
  const int wr = (w >> 1) * 64, wc = (w & 1) * WN;
  const int lrq = lane >> 2;     // row within 16-row staging group
  const int lg  = lane & 3;      // dest granule slot
  const int l15 = lane & 15, lg4 = lane >> 4;

  f32x4 acc[4][NREP];
  #pragma unroll
  for (int i=0;i<4;i++)
    #pragma unroll
    for (int j=0;j<NREP;j++) acc[i][j] = (f32x4){0.f,0.f,0.f,0.f};

  const int NT = K >> 5;

  auto stage = [&](int buf, int k0) {
    #pragma unroll
    for (int i = 0; i < IPW; ++i) {
      const int base = (w + i*4) * 16;           // wave-uniform group base row
      const int lr = base + lrq;
      const int gs = lg ^ ((lr >> 1) & 3);       // swizzled source granule
      const unsigned short* src;
      if (base < BM) src = A + (size_t)(row0 + lr) * lda + k0 + gs*8;
      else           src = B + (size_t)(col0 + lr - BM) * ldb + k0 + gs*8;
      gload16(src, &S[buf][base*32]);
    }
  };

  stage(0, 0);
  stage(1, 32);
  for (int kt = 0; kt < NT; ++kt) {
    const int cur = kt % 3;
    if (kt < NT-1) {
      if constexpr (IPW == 4) asm volatile("s_waitcnt vmcnt(4)" ::: "memory");
      else                    asm volatile("s_waitcnt vmcnt(3)" ::: "memory");
    } else {
      asm volatile("s_waitcnt vmcnt(0)" ::: "memory");
    }
    __builtin_amdgcn_s_barrier();
    asm volatile("" ::: "memory");
    if (kt + 2 < NT) stage((kt+2) % 3, (kt+2) << 5);

    const unsigned short* Sa = &S[cur][0];
    const unsigned short* Sb = &S[cur][BM*32];
    bf16x8 af[4], bfr[NREP];
    #pragma unroll
    for (int mi=0;mi<4;mi++){
      const int r = wr + mi*16 + l15;
      const int slot = lg4 ^ ((r >> 1) & 3);
      af[mi] = *(const bf16x8*)&Sa[r*32 + slot*8];
    }
    #pragma unroll
    for (int ni=0;ni<NREP;ni++){
      const int r = wc + ni*16 + l15;
      const int slot = lg4 ^ ((r >> 1) & 3);
      bfr[ni] = *(const bf16x8*)&Sb[r*32 + slot*8];
    }
    #pragma unroll
    for (int mi=0;mi<4;mi++)
      #pragma unroll
      for (int ni=0;ni<NREP;ni++)
        acc[mi][ni] = __builtin_amdgcn_mfma_f32_16x16x32_bf16(af[mi], bfr[ni], acc[mi][ni], 0, 0, 0);
    __builtin_amdgcn_sched_barrier(0);   // pin ds_read completion before next barrier
    asm volatile("" ::: "memory");
  }

  #pragma unroll
  for (int mi=0;mi<4;mi++){
    const int rb = row0 + wr + mi*16 + lg4*4;
    #pragma unroll
    for (int ni=0;ni<NREP;ni++){
      const int c = col0 + wc + ni*16 + l15;
      #pragma unroll
      for (int q=0;q<4;q++){
        const int r = rb + q;
        float v = acc[mi][ni][q];
        if constexpr (MODE == 0) {
          if (c < N) ((float*)out0)[(size_t)r*N + c] = bias ? v + bias[c] : v;
        } else if constexpr (MODE == 1) {
          if (c < N) { v += bias[c]; v = (v > 20.f) ? v : log1pf(__expf(v));
                       ((float*)out0)[(size_t)r*N + c] = v; }
        } else if constexpr (MODE == 2) {
          if (c < N) ((unsigned short*)out0)[(size_t)r*N + c] = f2bf(v);
        } else if constexpr (MODE == 3) {
          if (c < 2048) ((float*)out0)[(size_t)r*2048 + c] = v;
          else          ((float*)out1)[(size_t)r*2048 + (c - 2048)] = v;
        } else {
          if (c < 32) ((float*)out0)[(size_t)r*32 + c] = v;
          else if (c < N) ((unsigned short*)out1)[(size_t)r*2048 + (c - 32)] = f2bf(v);
        }
      }
    }
  }
}

// LayerNorm: read fp32 h, write bf16
__global__ __launch_bounds__(256)
void ln_k(const float* __restrict__ h, const float* __restrict__ gamma,
          const float* __restrict__ beta, unsigned short* __restrict__ hb)
{
  const int row = blockIdx.x;
  const float* p = h + (size_t)row * D_MODEL;
  float s = 0.f, s2 = 0.f;
  for (int i = threadIdx.x; i < D_MODEL; i += 256) { float v = p[i]; s += v; s2 += v*v; }
  #pragma unroll
  for (int off = 32; off; off >>= 1) { s += __shfl_down(s, off, 64); s2 += __shfl_down(s2, off, 64); }
  __shared__ float ss[4], ss2[4];
  __shared__ float smu, sinv;
  const int wid = threadIdx.x >> 6;
  if ((threadIdx.x & 63) == 0) { ss[wid] = s; ss2[wid] = s2; }
  __syncthreads();
  if (threadIdx.x == 0) {
    float S = ss[0]+ss[1]+ss[2]+ss[3];
    float S2 = ss2[0]+ss2[1]+ss2[2]+ss2[3];
    float mu = S * (1.f / D_MODEL);
    float var = S2 * (1.f / D_MODEL) - mu * mu;
    smu = mu; sinv = rsqrtf(var + 1e-5f);
  }
  __syncthreads();
  const float mu = smu, inv = sinv;
  unsigned short* q = hb + (size_t)row * D_MODEL;
  for (int i = threadIdx.x; i < D_MODEL; i += 256)
    q[i] = f2bf((p[i] - mu) * inv * gamma[i] + beta[i]);
}

// conv+silu: read xb fp32 [NTOK][2048], write u bf16
__global__ __launch_bounds__(256)
void conv_silu_k(const float* __restrict__ xb, const float* __restrict__ cw,
                 const float* __restrict__ cb, unsigned short* __restrict__ ub)
{
  const int idx = blockIdx.x * 256 + threadIdx.x;
  const int d  = idx & (D_INNER - 1);
  const int bt = idx >> 11;
  const int t  = bt & (SEQ - 1);
  float acc = cb[d];
  const float* base = xb + (size_t)bt * D_INNER + d;
  #pragma unroll
  for (int k = 0; k < D_CONV; ++k) {
    int tt = t + k - (D_CONV - 1);
    if (tt >= 0) acc = fmaf(cw[d*D_CONV + k], base[(ptrdiff_t)(k - (D_CONV-1)) * D_INNER], acc);
  }
  ub[idx] = f2bf(siluf(acc));
}

// ---- chunk-parallel scan; BC compact [NTOK][32] fp32 ----
__global__ __launch_bounds__(256)
void scan_p1(const float* __restrict__ dtb, const unsigned short* __restrict__ ub,
             const float* __restrict__ BC, const float* __restrict__ A_log,
             float* __restrict__ summ)
{
  const int bid = blockIdx.x;
  const int b = bid >> 7;
  const int c = (bid >> 3) & (NCHUNK - 1);
  const int d = ((bid & 7) << 8) + threadIdx.x;
  float A[D_STATE], hl[D_STATE];
  #pragma unroll
  for (int n = 0; n < D_STATE; ++n) { A[n] = -__expf(A_log[d*D_STATE + n]); hl[n] = 0.f; }
  float dtsum = 0.f;
  const size_t row0 = (size_t)b * SEQ + (size_t)c * CHUNK;
  for (int t = 0; t < CHUNK; ++t) {
    const size_t r = row0 + t;
    const float dtv = dtb[r*D_INNER + d];
    const float uv  = bf2f(ub[r*D_INNER + d]);
    const float du = dtv * uv;
    dtsum += dtv;
    const float* Bp = BC + r*32;
    #pragma unroll
    for (int n = 0; n < D_STATE; ++n) {
      float dA = __expf(dtv * A[n]);
      hl[n] = fmaf(dA, hl[n], du * Bp[n]);
    }
  }
  float* s = summ + (((size_t)b*NCHUNK + c)*32)*D_INNER + d;
  #pragma unroll
  for (int n = 0; n < D_STATE; ++n) {
    s[(size_t)n*D_INNER]      = __expf(A[n] * dtsum);
    s[(size_t)(16+n)*D_INNER] = hl[n];
  }
}

__global__ __launch_bounds__(256)
void scan_p2(float* __restrict__ summ, const float* __restrict__ h0,
             float* __restrict__ outH)
{
  const int b = blockIdx.x >> 3;
  const int d = ((blockIdx.x & 7) << 8) + threadIdx.x;
  float h[D_STATE];
  #pragma unroll
  for (int n = 0; n < D_STATE; ++n) h[n] = h0[((size_t)b*D_INNER + d)*D_STATE + n];
  for (int c = 0; c < NCHUNK; ++c) {
    float* s = summ + (((size_t)b*NCHUNK + c)*32)*D_INNER + d;
    #pragma unroll
    for (int n = 0; n < D_STATE; ++n) {
      float p = s[(size_t)n*D_INNER];
      float l = s[(size_t)(16+n)*D_INNER];
      s[(size_t)n*D_INNER] = h[n];
      h[n] = fmaf(p, h[n], l);
    }
  }
  #pragma unroll
  for (int n = 0; n < D_STATE; ++n)
    outH[((size_t)b*D_INNER + d)*D_STATE + n] = h[n];
}

__global__ __launch_bounds__(256)
void scan_p3(const float* __restrict__ dtb, const unsigned short* __restrict__ ub,
             const float* __restrict__ zb, const float* __restrict__ BC,
             const float* __restrict__ A_log, const float* __restrict__ D_skip,
             const float* __restrict__ summ, unsigned short* __restrict__ yb)
{
  const int bid = blockIdx.x;
  const int b = bid >> 7;
  const int c = (bid >> 3) & (NCHUNK - 1);
  const int d = ((bid & 7) << 8) + threadIdx.x;
  float A[D_STATE], h[D_STATE];
  const float* s = summ + (((size_t)b*NCHUNK + c)*32)*D_INNER + d;
  #pragma unroll
  for (int n = 0; n < D_STATE; ++n) {
    A[n] = -__expf(A_log[d*D_STATE + n]);
    h[n] = s[(size_t)n*D_INNER];
  }
  const float Ds = D_skip[d];
  const size_t row0 = (size_t)b * SEQ + (size_t)c * CHUNK;
  for (int t = 0; t < CHUNK; ++t) {
    const size_t r = row0 + t;
    const float dtv = dtb[r*D_INNER + d];
    const float uv  = bf2f(ub[r*D_INNER + d]);
    const float zv  = zb[r*D_INNER + d];
    const float du = dtv * uv;
    const float* Bp = BC + r*32;
    float y = 0.f;
    #pragma unroll
    for (int n = 0; n < D_STATE; ++n) {
      float dA = __expf(dtv * A[n]);
      h[n] = fmaf(dA, h[n], du * Bp[n]);
      y = fmaf(h[n], Bp[16+n], y);
    }
    y = fmaf(uv, Ds, y);
    yb[r*D_INNER + d] = f2bf(y * siluf(zv));
  }
}

extern "C" void kernel_launch(void* const* d_in, const int* in_sizes, int n_in,
                              void* d_out, int out_size, void* d_ws, size_t ws_size,
                              hipStream_t stream) {
  const float* x          = (const float*)d_in[0];
  const float* h0         = (const float*)d_in[1];
  const float* W_in_wrap  = (const float*)d_in[2];
  const float* b_in_wrap  = (const float*)d_in[3];
  const float* ln_g       = (const float*)d_in[4];
  const float* ln_b       = (const float*)d_in[5];
  const float* W_in       = (const float*)d_in[6];
  const float* conv_w     = (const float*)d_in[7];
  const float* conv_b     = (const float*)d_in[8];
  const float* W_x        = (const float*)d_in[9];
  const float* W_dt       = (const float*)d_in[10];
  const float* b_dt       = (const float*)d_in[11];
  const float* A_log      = (const float*)d_in[12];
  const float* D_skip     = (const float*)d_in[13];
  const float* W_out      = (const float*)d_in[14];
  const float* W_out_wrap = (const float*)d_in[15];
  const float* b_out_wrap = (const float*)d_in[16];

  float* out  = (float*)d_out;                       // (B,T,OUT_DIM)
  float* outH = out + (size_t)NTOK * OUT_DIM;        // (B,D_INNER,D_STATE)

  char* ws = (char*)d_ws;
  auto at = [&](size_t kb){ return (void*)(ws + kb*1024); };
  float*          hbuf = (float*)at(0);        // 8 MB fp32 h (then summ)
  float*          summ = hbuf;
  float*          xb   = (float*)at(8192);     // 16 MB fp32 x_branch (then dtb)
  float*          dtb  = xb;
  float*          zb   = (float*)at(24576);    // 16 MB fp32 z
  unsigned short* ub   = (unsigned short*)at(40960);  // 8 MB bf16 u (xb16 early)
  unsigned short* xb16 = ub;                          // 1 MB bf16 x-cast (dead before conv)
  unsigned short* gb   = (unsigned short*)at(49152);  // 8 MB bf16 gate (WiwT early; yb later)
  unsigned short* WiwT = gb;                          // 512 KB (dead before proj)
  unsigned short* yb   = gb;
  unsigned short* hb   = (unsigned short*)at(57344);  // 4 MB bf16 h_ln (then tmpb)
  unsigned short* tmpb = hb;
  float*          BC   = (float*)at(61440);    // 256 KB fp32 [NTOK][32]
  unsigned short* WinT = (unsigned short*)at(61696);  // 8 MB   [4096][1024]
  unsigned short* WxT  = (unsigned short*)at(69888);  // 8.5 MB [2176pad][2048]
  unsigned short* WdtT = (unsigned short*)at(78592);  // 8 MB   [2048][2048]
  unsigned short* WoutT= (unsigned short*)at(86784);  // 4 MB   [1024][2048]
  unsigned short* WwrT = (unsigned short*)at(90880);  // 512 KB [256][1024]  (ends 89.25 MB)

  dim3 blk(256);
  // x -> bf16; W_in_wrap^T
  cast_bf16_k<<<dim3(NTOK*IN_DIM/4/256), blk, 0, stream>>>(x, xb16, NTOK*IN_DIM/4);
  transpose_cast<<<dim3(1024/32, 256/32), blk, 0, stream>>>(W_in_wrap, WiwT, 256, 1024);
  // 1) h = x @ W_in_wrap + b_in_wrap  (bf16 MFMA, K=256)
  gemm_bf16<64,0><<<dim3(1024/64, NTOK/128), blk, 0, stream>>>(xb16, WiwT, NTOK, 1024, 256,
                                                               256, 256, b_in_wrap, hbuf, nullptr);
  // 2) LayerNorm -> bf16
  ln_k<<<dim3(NTOK), blk, 0, stream>>>(hbuf, ln_g, ln_b, hb);
  // weight transposes (fp32 -> bf16, [R][C] -> [C][R])
  transpose_cast<<<dim3(4096/32, 1024/32), blk, 0, stream>>>(W_in, WinT, 1024, 4096);
  transpose_cast<<<dim3(2080/32, 2048/32), blk, 0, stream>>>(W_x, WxT, 2048, 2080);
  transpose_cast<<<dim3(2048/32, 2048/32), blk, 0, stream>>>(W_dt, WdtT, 2048, 2048);
  transpose_cast<<<dim3(1024/32, 2048/32), blk, 0, stream>>>(W_out, WoutT, 2048, 1024);
  transpose_cast<<<dim3(256/32, 1024/32), blk, 0, stream>>>(W_out_wrap, WwrT, 1024, 256);
  // 3) xz = h @ W_in -> xb fp32 | zb fp32   (512 blocks)
  gemm_bf16<128,3><<<dim3(4096/128, NTOK/128), blk, 0, stream>>>(hb, WinT, NTOK, 4096, 1024,
                                                                 1024, 1024, nullptr, xb, zb);
  // 4) u = silu(conv(xb)) -> bf16
  conv_silu_k<<<dim3(NTOK*D_INNER/256), blk, 0, stream>>>(xb, conv_w, conv_b, ub);
  // 5) proj = u @ W_x -> BC fp32 [.,32] | g bf16 [.,2048]  (528 blocks)
  gemm_bf16<64,4><<<dim3(2112/64, NTOK/128), blk, 0, stream>>>(ub, WxT, NTOK, PROJ_N, 2048,
                                                               2048, 2048, nullptr, BC, gb);
  // 6) dt = softplus(g @ W_dt + b_dt) -> fp32 (over xb)   (512 blocks)
  gemm_bf16<64,1><<<dim3(2048/64, NTOK/128), blk, 0, stream>>>(gb, WdtT, NTOK, 2048, 2048,
                                                               2048, 2048, b_dt, dtb, nullptr);
  // 7) chunk-parallel scan
  scan_p1<<<dim3(BATCH*NCHUNK*(D_INNER/256)), blk, 0, stream>>>(dtb, ub, BC, A_log, summ);
  scan_p2<<<dim3(BATCH*(D_INNER/256)), blk, 0, stream>>>(summ, h0, outH);
  scan_p3<<<dim3(BATCH*NCHUNK*(D_INNER/256)), blk, 0, stream>>>(dtb, ub, zb, BC, A_log, D_skip, summ, yb);
  // 8) tmp = y @ W_out -> bf16 (over hb)    (256 blocks)
  gemm_bf16<64,2><<<dim3(1024/64, NTOK/128), blk, 0, stream>>>(yb, WoutT, NTOK, 1024, 2048,
                                                               2048, 2048, nullptr, tmpb, nullptr);
  // 9) out = tmp @ W_out_wrap + b_out_wrap (fp32 out)
  gemm_bf16<64,0><<<dim3(256/64, NTOK/128), blk, 0, stream>>>(tmpb, WwrT, NTOK, 256, 1024,
                                                              1024, 1024, b_out_wrap, out, nullptr);
}